// Round 2
// baseline (97.111 us; speedup 1.0000x reference)
//
#include <hip/hip_runtime.h>
#include <math.h>

// Problem constants
constexpr int B = 2, C = 16, H = 128, W = 128;
constexpr int KK = 19, PAD = 9;

// Padded x: rows 0..145 (= original -9..136), row stride 148 (mult of 4)
constexpr int XROWS = 146, XS = 148;
constexpr int XCH = XROWS * XS;                    // 21608
constexpr size_t XPAD_ELEMS = (size_t)B * C * XCH; // 691,456

// Padded y (2 half-planes per channel): rows 0..129 (= original -1..128),
// row stride 136; original col w lives at padded col w+4 (16B-aligned stores)
constexpr int YROWS = 130, YS = 136;
constexpr int YCH = YROWS * YS;                          // 17680
constexpr int YPLANES = 2 * C;                           // half*16 + c
constexpr size_t YPAD_ELEMS = (size_t)B * YPLANES * YCH; // 1,131,520

// ---------------------------------------------------------------------------
// Kernel 1: 3x3 conv (pad 1) + exact GELU -> padded x buffer
// ---------------------------------------------------------------------------
__global__ __launch_bounds__(256) void conv1_gelu(
    const float* __restrict__ in,   // [B,16,128,128]
    const float* __restrict__ w1,   // [16,16,3,3]
    const float* __restrict__ b1,   // [16]
    float* __restrict__ xpad)       // [B,16,146,148], pads pre-zeroed
{
    __shared__ float ws[16 * 16 * 9];
    for (int i = threadIdx.x; i < 16 * 16 * 9; i += 256) ws[i] = w1[i];
    __syncthreads();

    int t  = blockIdx.x * 256 + threadIdx.x;
    int w  = t & 127;
    int h  = (t >> 7) & 127;
    int oc = (t >> 14) & 15;
    int b  = t >> 18;

    float acc = b1[oc];
    const float* inb = in + (size_t)b * C * H * W;
    const float* wr  = ws + oc * 144;

    for (int dy = 0; dy < 3; ++dy) {
        int y = h + dy - 1;
        if ((unsigned)y >= (unsigned)H) continue;
        for (int dx = 0; dx < 3; ++dx) {
            int x = w + dx - 1;
            if ((unsigned)x >= (unsigned)W) continue;
            const float* ip = inb + y * W + x;
            const float* wp = wr + dy * 3 + dx;
            #pragma unroll
            for (int ic = 0; ic < 16; ++ic)
                acc += ip[ic * (H * W)] * wp[ic * 9];
        }
    }
    float g = 0.5f * acc * (1.0f + erff(acc * 0.70710678f));
    xpad[((size_t)(b * C + oc) * XROWS + (h + PAD)) * XS + (w + PAD)] = g;
}

// ---------------------------------------------------------------------------
// Kernel 2: per-pixel 19x19 convolution, split over kh halves.
// Thread = 4 consecutive w-pixels x 1 channel x 1 kh-half.
// Block = 256 thr: 8 pixel-quads (32 px) x 16 ch x 2 halves. Grid = 1024.
// kern reads are float4 (16B/lane); x rows staged as 6 float4 in registers.
// ---------------------------------------------------------------------------
__global__ __launch_bounds__(256) void kpn19(
    const float* __restrict__ xpad,  // [B,16,146,148]
    const float* __restrict__ kern,  // [B,361,128,128]
    float* __restrict__ ypad)        // [B,32,130,136], pads pre-zeroed
{
    int blk  = blockIdx.x;           // 1024
    int wblk = blk & 3;              // 32-px column block
    int h    = (blk >> 2) & 127;
    int b    = blk >> 9;

    int pg   = threadIdx.x & 7;
    int c    = (threadIdx.x >> 3) & 15;
    int half = threadIdx.x >> 7;     // wave-uniform
    int w0   = wblk * 32 + pg * 4;

    float4 acc = make_float4(0.f, 0.f, 0.f, 0.f);

    const float* xb = xpad + (size_t)(b * C + c) * XCH;
    const float* kbase = kern + ((size_t)(b * 361 + half * 190) * H + h) * W + w0;
    const int nkh = 10 - half;       // half0: kh 0..9, half1: kh 10..18

    for (int khh = 0; khh < nkh; ++khh) {
        int kh = half * 10 + khh;
        const float* xr = xb + (size_t)(h + kh) * XS + w0;   // 16B-aligned
        float xv[24];
        #pragma unroll
        for (int q = 0; q < 6; ++q) {
            float4 xq = *(const float4*)(xr + 4 * q);
            xv[4 * q + 0] = xq.x; xv[4 * q + 1] = xq.y;
            xv[4 * q + 2] = xq.z; xv[4 * q + 3] = xq.w;
        }
        const float* kp = kbase + (size_t)khh * 19 * H * W;
        #pragma unroll
        for (int kw = 0; kw < KK; ++kw) {
            float4 kq = *(const float4*)(kp + (size_t)kw * H * W);
            acc.x = fmaf(xv[kw + 0], kq.x, acc.x);
            acc.y = fmaf(xv[kw + 1], kq.y, acc.y);
            acc.z = fmaf(xv[kw + 2], kq.z, acc.z);
            acc.w = fmaf(xv[kw + 3], kq.w, acc.w);
        }
    }

    int plane = b * YPLANES + half * 16 + c;
    *(float4*)(ypad + ((size_t)plane * YROWS + (h + 1)) * YS + (4 + w0)) = acc;
}

// ---------------------------------------------------------------------------
// Kernel 3: 3x3 conv (pad 1) over 32 partial planes + sigmoid -> d_out
// ---------------------------------------------------------------------------
__global__ __launch_bounds__(256) void conv2_sig(
    const float* __restrict__ ypad,  // [B,32,130,136]
    const float* __restrict__ w2,    // [16,16,3,3]
    const float* __restrict__ b2,    // [16]
    float* __restrict__ out)         // [B,16,128,128]
{
    __shared__ float ws[16 * 16 * 9];
    for (int i = threadIdx.x; i < 16 * 16 * 9; i += 256) ws[i] = w2[i];
    __syncthreads();

    int t  = blockIdx.x * 256 + threadIdx.x;
    int w  = t & 127;
    int h  = (t >> 7) & 127;
    int oc = (t >> 14) & 15;
    int b  = t >> 18;

    float acc = b2[oc];
    const float* wr = ws + oc * 144;

    #pragma unroll
    for (int half = 0; half < 2; ++half) {
        #pragma unroll 4
        for (int ic = 0; ic < 16; ++ic) {
            const float* yc = ypad + ((size_t)((b * 2 + half) * 16 + ic) * YROWS + h) * YS + (w + 3);
            const float* wp = wr + ic * 9;
            #pragma unroll
            for (int dy = 0; dy < 3; ++dy) {
                #pragma unroll
                for (int dx = 0; dx < 3; ++dx)
                    acc = fmaf(yc[dy * YS + dx], wp[dy * 3 + dx], acc);
            }
        }
    }
    out[t] = 1.0f / (1.0f + expf(-acc));
}

// ---------------------------------------------------------------------------
extern "C" void kernel_launch(void* const* d_in, const int* in_sizes, int n_in,
                              void* d_out, int out_size, void* d_ws, size_t ws_size,
                              hipStream_t stream)
{
    const float* input  = (const float*)d_in[0];
    const float* kernel = (const float*)d_in[1];
    const float* w1     = (const float*)d_in[2];
    const float* b1     = (const float*)d_in[3];
    const float* w2     = (const float*)d_in[4];
    const float* b2     = (const float*)d_in[5];
    float* out = (float*)d_out;

    float* xpad = (float*)d_ws;
    float* ypad = xpad + XPAD_ELEMS;

    hipMemsetAsync(d_ws, 0, (XPAD_ELEMS + YPAD_ELEMS) * sizeof(float), stream);

    int n1 = B * C * H * W;                        // 524288
    conv1_gelu<<<n1 / 256, 256, 0, stream>>>(input, w1, b1, xpad);

    kpn19<<<B * H * (W / 32), 256, 0, stream>>>(xpad, kernel, ypad);

    conv2_sig<<<n1 / 256, 256, 0, stream>>>(ypad, w2, b2, out);
}

// Round 3
// 82.083 us; speedup vs baseline: 1.1831x; 1.1831x over previous
//
#include <hip/hip_runtime.h>
#include <math.h>

constexpr int B = 2, C = 16, H = 128, W = 128;
constexpr int KK = 19;

// xpad: [B,16,146,148]; orig (h,w) -> (h+9, w+9); zero pads elsewhere
constexpr int XR = 146, XS = 148, XCH = XR * XS;
constexpr size_t XPAD_ELEMS = (size_t)B * C * XCH;          // 691,456

// ypad: [B,16,130,136]; orig (h,w) -> (h+1, w+4); zero pads elsewhere
constexpr int YR = 130, YS = 136, YCH = YR * YS;
constexpr size_t YPAD_ELEMS = (size_t)B * C * YCH;          // 565,760

// ---------------------------------------------------------------------------
// Kernel 1: 3x3 conv (pad 1) + exact GELU -> xpad. Thread = 4 px, oc uniform
// per wave. Weights in LDS (broadcast reads).
// ---------------------------------------------------------------------------
__global__ __launch_bounds__(256) void conv1_gelu(
    const float* __restrict__ in,   // [B,16,128,128]
    const float* __restrict__ w1,   // [16,16,3,3]
    const float* __restrict__ b1,   // [16]
    float* __restrict__ xpad)
{
    __shared__ float ws[16 * 16 * 9];
    __shared__ float bs[16];
    for (int i = threadIdx.x; i < 16 * 16 * 9; i += 256) ws[i] = w1[i];
    if (threadIdx.x < 16) bs[threadIdx.x] = b1[threadIdx.x];
    __syncthreads();

    int t  = blockIdx.x * 256 + threadIdx.x;
    int wq = t & 31;                 // 32 col-quads
    int h  = (t >> 5) & 127;
    int oc = (t >> 12) & 15;         // wave-uniform
    int b  = t >> 16;
    int w0 = wq * 4;

    float4 acc = make_float4(bs[oc], bs[oc], bs[oc], bs[oc]);
    const float* inb = in + (size_t)b * C * H * W;
    const float* wr  = ws + oc * 144;
    const float4 zero4 = make_float4(0.f, 0.f, 0.f, 0.f);

    for (int ic = 0; ic < 16; ++ic) {
        const float* ip = inb + ic * (H * W);
        #pragma unroll
        for (int dy = 0; dy < 3; ++dy) {
            int r = h + dy - 1;
            if ((unsigned)r >= (unsigned)H) continue;   // zero pad row
            const float* rp = ip + r * W;
            float4 Lq = (w0 >= 4)   ? *(const float4*)(rp + w0 - 4) : zero4;
            float4 Mq =               *(const float4*)(rp + w0);
            float4 Rq = (w0 <= 120) ? *(const float4*)(rp + w0 + 4) : zero4;
            float w0v = wr[ic * 9 + dy * 3 + 0];
            float w1v = wr[ic * 9 + dy * 3 + 1];
            float w2v = wr[ic * 9 + dy * 3 + 2];
            acc.x = fmaf(w0v, Lq.w, fmaf(w1v, Mq.x, fmaf(w2v, Mq.y, acc.x)));
            acc.y = fmaf(w0v, Mq.x, fmaf(w1v, Mq.y, fmaf(w2v, Mq.z, acc.y)));
            acc.z = fmaf(w0v, Mq.y, fmaf(w1v, Mq.z, fmaf(w2v, Mq.w, acc.z)));
            acc.w = fmaf(w0v, Mq.z, fmaf(w1v, Mq.w, fmaf(w2v, Rq.x, acc.w)));
        }
    }

    float* xp = xpad + ((size_t)(b * C + oc) * XR + (h + 9)) * XS + (w0 + 9);
    xp[0] = 0.5f * acc.x * (1.0f + erff(acc.x * 0.70710678f));
    xp[1] = 0.5f * acc.y * (1.0f + erff(acc.y * 0.70710678f));
    xp[2] = 0.5f * acc.z * (1.0f + erff(acc.z * 0.70710678f));
    xp[3] = 0.5f * acc.w * (1.0f + erff(acc.w * 0.70710678f));
}

// ---------------------------------------------------------------------------
// Kernel 2: per-pixel 19x19 conv. Tile = 64 px x 16 ch, kh split in halves.
// Thread = 4 px x 2 ch (c, c+8) x 1 half. kern staged in LDS (double-buffered
// per kh-step, reg-staged with early issue). Halves reduced via LDS at end.
// ---------------------------------------------------------------------------
__global__ __launch_bounds__(256, 2) void kpn19(
    const float* __restrict__ xpad,  // [B,16,146,148]
    const float* __restrict__ kern,  // [B,361,128,128]
    float* __restrict__ ypad)        // [B,16,130,136]
{
    __shared__ float kbuf[2][38][64];   // 19,456 B; [buf][pp][px]  pp: half*19+kw

    int blk = blockIdx.x;            // 512 = wb(2) x h(128) x b(2)
    int wb  = blk & 1;
    int h   = (blk >> 1) & 127;
    int b   = blk >> 8;

    int tid  = threadIdx.x;
    int pq   = tid & 15;             // 16 px-quads = 64 px
    int cg   = (tid >> 4) & 7;       // channels cg, cg+8
    int half = tid >> 7;             // wave-uniform (waves 0,1 vs 2,3)
    int w0q  = wb * 64 + pq * 4;

    const float* kb = kern + (size_t)b * 361 * H * W + (size_t)h * W + wb * 64;

    float4 acc0 = make_float4(0.f, 0.f, 0.f, 0.f);
    float4 acc1 = make_float4(0.f, 0.f, 0.f, 0.f);
    float4 tmp[3];

    // --- staging helpers: 608 16B-chunks per kh-step (38 planes x 64 px) ---
    auto stage_load = [&](int kh0) {
        #pragma unroll
        for (int j = 0; j < 3; ++j) {
            int f = tid + j * 256;
            if (f < 608) {
                int pp = f >> 4, q = f & 15;
                int p  = (pp < 19) ? (kh0 * 19 + pp)
                                   : ((kh0 + 10) * 19 + (pp - 19));
                if (p > 360) p = 360;    // kh0==9 half1 row invalid; never read
                tmp[j] = *(const float4*)(kb + (size_t)p * (H * W) + q * 4);
            }
        }
    };
    auto stage_write = [&](int buf) {
        #pragma unroll
        for (int j = 0; j < 3; ++j) {
            int f = tid + j * 256;
            if (f < 608)
                *(float4*)(&kbuf[buf][f >> 4][(f & 15) * 4]) = tmp[j];
        }
    };

    // --- prologue: stage kh-step 0 into buf 0 ---
    stage_load(0);
    stage_write(0);
    __syncthreads();

    for (int khh = 0; khh < 10; ++khh) {
        int cur = khh & 1;
        if (khh < 9) stage_load(khh + 1);       // issue early: hides under compute

        if (!(half == 1 && khh == 9)) {         // half1 has only 9 rows
            int kh = half * 10 + khh;
            const float* xr0 = xpad + ((size_t)(b * C + cg) * XR + (h + kh)) * XS + w0q;
            const float* xr1 = xr0 + (size_t)8 * XCH;
            float xv0[24], xv1[24];
            #pragma unroll
            for (int q6 = 0; q6 < 6; ++q6) {
                float4 a = *(const float4*)(xr0 + q6 * 4);
                xv0[q6 * 4 + 0] = a.x; xv0[q6 * 4 + 1] = a.y;
                xv0[q6 * 4 + 2] = a.z; xv0[q6 * 4 + 3] = a.w;
                float4 c4 = *(const float4*)(xr1 + q6 * 4);
                xv1[q6 * 4 + 0] = c4.x; xv1[q6 * 4 + 1] = c4.y;
                xv1[q6 * 4 + 2] = c4.z; xv1[q6 * 4 + 3] = c4.w;
            }
            const float4* kr = (const float4*)(&kbuf[cur][half * 19][0]);
            #pragma unroll
            for (int kw = 0; kw < KK; ++kw) {
                float4 kq = kr[kw * 16 + pq];   // broadcast across cg groups
                acc0.x = fmaf(xv0[kw + 0], kq.x, acc0.x);
                acc0.y = fmaf(xv0[kw + 1], kq.y, acc0.y);
                acc0.z = fmaf(xv0[kw + 2], kq.z, acc0.z);
                acc0.w = fmaf(xv0[kw + 3], kq.w, acc0.w);
                acc1.x = fmaf(xv1[kw + 0], kq.x, acc1.x);
                acc1.y = fmaf(xv1[kw + 1], kq.y, acc1.y);
                acc1.z = fmaf(xv1[kw + 2], kq.z, acc1.z);
                acc1.w = fmaf(xv1[kw + 3], kq.w, acc1.w);
            }
        }

        __syncthreads();                        // all reads of kbuf done
        if (khh < 9) stage_write(cur ^ 1);      // write next kh-step
        __syncthreads();                        // writes visible
    }

    // --- reduce the two kh-halves via LDS, half 0 writes y ---
    float* red = &kbuf[0][0][0];
    int o = (cg * 16 + pq) * 8;
    if (half == 1) {
        red[o + 0] = acc0.x; red[o + 1] = acc0.y;
        red[o + 2] = acc0.z; red[o + 3] = acc0.w;
        red[o + 4] = acc1.x; red[o + 5] = acc1.y;
        red[o + 6] = acc1.z; red[o + 7] = acc1.w;
    }
    __syncthreads();
    if (half == 0) {
        acc0.x += red[o + 0]; acc0.y += red[o + 1];
        acc0.z += red[o + 2]; acc0.w += red[o + 3];
        acc1.x += red[o + 4]; acc1.y += red[o + 5];
        acc1.z += red[o + 6]; acc1.w += red[o + 7];
        float* yp = ypad + ((size_t)(b * C + cg) * YR + (h + 1)) * YS + (w0q + 4);
        *(float4*)yp = acc0;
        *(float4*)(yp + (size_t)8 * YCH) = acc1;
    }
}

// ---------------------------------------------------------------------------
// Kernel 3: 3x3 conv (pad 1) + sigmoid -> out. Thread = 4 px, branch-free
// reads from padded y.
// ---------------------------------------------------------------------------
__global__ __launch_bounds__(256) void conv2_sig(
    const float* __restrict__ ypad,  // [B,16,130,136]
    const float* __restrict__ w2,    // [16,16,3,3]
    const float* __restrict__ b2,    // [16]
    float* __restrict__ out)         // [B,16,128,128]
{
    __shared__ float ws[16 * 16 * 9];
    __shared__ float bs[16];
    for (int i = threadIdx.x; i < 16 * 16 * 9; i += 256) ws[i] = w2[i];
    if (threadIdx.x < 16) bs[threadIdx.x] = b2[threadIdx.x];
    __syncthreads();

    int t  = blockIdx.x * 256 + threadIdx.x;
    int wq = t & 31;
    int h  = (t >> 5) & 127;
    int oc = (t >> 12) & 15;
    int b  = t >> 16;
    int w0 = wq * 4;

    float4 acc = make_float4(bs[oc], bs[oc], bs[oc], bs[oc]);
    const float* yb = ypad + (size_t)b * C * YCH;
    const float* wr = ws + oc * 144;

    for (int ic = 0; ic < 16; ++ic) {
        const float* yc = yb + (size_t)ic * YCH + (size_t)h * YS + w0;
        #pragma unroll
        for (int dy = 0; dy < 3; ++dy) {
            // padded row h+dy covers orig rows h-1..h+1; cols w0+3..w0+8
            const float* rp = yc + dy * YS;
            float4 A = *(const float4*)(rp);
            float4 Bq = *(const float4*)(rp + 4);
            float4 Cq = *(const float4*)(rp + 8);
            float w0v = wr[ic * 9 + dy * 3 + 0];
            float w1v = wr[ic * 9 + dy * 3 + 1];
            float w2v = wr[ic * 9 + dy * 3 + 2];
            acc.x = fmaf(w0v, A.w,  fmaf(w1v, Bq.x, fmaf(w2v, Bq.y, acc.x)));
            acc.y = fmaf(w0v, Bq.x, fmaf(w1v, Bq.y, fmaf(w2v, Bq.z, acc.y)));
            acc.z = fmaf(w0v, Bq.y, fmaf(w1v, Bq.z, fmaf(w2v, Bq.w, acc.z)));
            acc.w = fmaf(w0v, Bq.z, fmaf(w1v, Bq.w, fmaf(w2v, Cq.x, acc.w)));
        }
    }

    float4 r;
    r.x = 1.0f / (1.0f + expf(-acc.x));
    r.y = 1.0f / (1.0f + expf(-acc.y));
    r.z = 1.0f / (1.0f + expf(-acc.z));
    r.w = 1.0f / (1.0f + expf(-acc.w));
    *(float4*)(out + (size_t)t * 0 + (((size_t)(b * C + oc) * H + h) * W + w0)) = r;
}

// ---------------------------------------------------------------------------
extern "C" void kernel_launch(void* const* d_in, const int* in_sizes, int n_in,
                              void* d_out, int out_size, void* d_ws, size_t ws_size,
                              hipStream_t stream)
{
    const float* input  = (const float*)d_in[0];
    const float* kernel = (const float*)d_in[1];
    const float* w1     = (const float*)d_in[2];
    const float* b1     = (const float*)d_in[3];
    const float* w2     = (const float*)d_in[4];
    const float* b2     = (const float*)d_in[5];
    float* out = (float*)d_out;

    float* xpad = (float*)d_ws;
    float* ypad = xpad + XPAD_ELEMS;

    hipMemsetAsync(d_ws, 0, (XPAD_ELEMS + YPAD_ELEMS) * sizeof(float), stream);

    conv1_gelu<<<512, 256, 0, stream>>>(input, w1, b1, xpad);
    kpn19<<<512, 256, 0, stream>>>(xpad, kernel, ypad);
    conv2_sig<<<512, 256, 0, stream>>>(ypad, w2, b2, out);
}